// Round 4
// baseline (359.611 us; speedup 1.0000x reference)
//
#include <hip/hip_runtime.h>

#define NJ   55
#define BLK  64                      // one wave per block: no barriers anywhere
#define SLABF (BLK * NJ)             // 3520 floats = 14080 B LDS -> 11 blocks/CU
#define STG  14                      // 13 full float4 rounds + 48-lane tail

// Software-pipelined wave-autonomous LBS:
//   iteration i: [issue points_i + 14x global_load_dwordx4 for slab i+1 into VGPRs]
//                [compute slab i from LDS: ds_read (lgkm) + FMA — vmem stays in flight]
//                [store out_i] [drain vmcnt, commit VGPRs -> LDS (wave-private, no barrier)]
// Staging loads ride out their latency UNDER the compute phase (separate counters:
// staging=vmcnt, compute=lgkm), so every wave keeps ~14 KB outstanding continuously.
__global__ __launch_bounds__(BLK, 3) void lbs_kernel(
    const float* __restrict__ points,
    const float* __restrict__ weights,
    const float* __restrict__ se3,
    float* __restrict__ out,
    int n_verts, int n_slabs, int gstride)
{
    __shared__ __align__(16) float s_w[SLABF];
    const int lane = threadIdx.x;

    int s = blockIdx.x;
    if (s >= n_slabs) return;

    // ---- prologue: stage slab s into LDS (through VGPRs)
    {
        const int rows = min(BLK, n_verts - s * BLK);
        if (rows == BLK) {
            const float4* src = (const float4*)(weights + (size_t)s * SLABF);
            float4* dst = (float4*)s_w;
            #pragma unroll
            for (int i = 0; i < STG - 1; ++i) dst[lane + i * BLK] = src[lane + i * BLK];
            if (lane < 48) dst[lane + (STG - 1) * BLK] = src[lane + (STG - 1) * BLK];
        } else {
            const float* src = weights + (size_t)s * SLABF;
            for (int i = lane; i < rows * NJ; i += BLK) s_w[i] = src[i];
        }
    }

    for (;;) {
        const int snext = s + gstride;
        const bool have_next = (snext < n_slabs);

        const int n = s * BLK + lane;
        const bool act = (n < n_verts);
        const int nc = act ? n : (n_verts - 1);

        // points for current slab — issued FIRST so the later vmcnt for px/py/pz
        // (in-order counter) doesn't force the staging loads to drain
        const float px = points[nc * 3 + 0];
        const float py = points[nc * 3 + 1];
        const float pz = points[nc * 3 + 2];

        // issue next slab's staging loads into VGPRs (in flight during compute)
        float4 stg[STG];
        bool full_next = false;
        if (have_next) {
            const int rows = min(BLK, n_verts - snext * BLK);
            full_next = (rows == BLK);
            if (full_next) {
                const float4* src = (const float4*)(weights + (size_t)snext * SLABF);
                #pragma unroll
                for (int i = 0; i < STG - 1; ++i) stg[i] = src[lane + i * BLK];
                if (lane < 48) stg[STG - 1] = src[lane + (STG - 1) * BLK];
            }
        }

        // ---- compute slab s from LDS (lgkm only — staging vmem stays in flight)
        float a[12];
        #pragma unroll
        for (int e = 0; e < 12; ++e) a[e] = 0.f;

        const float* wr = &s_w[lane * NJ];       // stride 55: 2-way bank alias = free
        const float4* M = (const float4*)se3;    // uniform addr -> s_load, K$-cached

        #pragma unroll 5
        for (int j = 0; j < NJ; ++j) {
            const float w = wr[j];
            const float4 r0 = M[j * 4 + 0];
            const float4 r1 = M[j * 4 + 1];
            const float4 r2 = M[j * 4 + 2];      // row 3 of each SE3 unused
            a[0] += w * r0.x; a[1] += w * r0.y; a[2]  += w * r0.z; a[3]  += w * r0.w;
            a[4] += w * r1.x; a[5] += w * r1.y; a[6]  += w * r1.z; a[7]  += w * r1.w;
            a[8] += w * r2.x; a[9] += w * r2.y; a[10] += w * r2.z; a[11] += w * r2.w;
        }

        if (act) {
            float* po = out + (size_t)n * 3;
            po[0] = a[0] * px + a[1] * py + a[2]  * pz + a[3];
            po[1] = a[4] * px + a[5] * py + a[6]  * pz + a[7];
            po[2] = a[8] * px + a[9] * py + a[10] * pz + a[11];
        }

        if (!have_next) return;

        // ---- commit staged slab to LDS (vmcnt drains here, AFTER compute).
        // Same wave: DS pipe is in-order per wave, so writes can't pass the
        // compute's reads — no barrier needed.
        if (full_next) {
            float4* dst = (float4*)s_w;
            #pragma unroll
            for (int i = 0; i < STG - 1; ++i) dst[lane + i * BLK] = stg[i];
            if (lane < 48) dst[lane + (STG - 1) * BLK] = stg[STG - 1];
        } else {
            const int rows = n_verts - snext * BLK;
            const float* src = weights + (size_t)snext * SLABF;
            for (int i = lane; i < rows * NJ; i += BLK) s_w[i] = src[i];
        }
        s = snext;
    }
}

extern "C" void kernel_launch(void* const* d_in, const int* in_sizes, int n_in,
                              void* d_out, int out_size, void* d_ws, size_t ws_size,
                              hipStream_t stream) {
    const float* points  = (const float*)d_in[0];
    const float* weights = (const float*)d_in[1];
    const float* se3     = (const float*)d_in[2];
    float* out = (float*)d_out;

    const int n_verts = in_sizes[0] / 3;                 // points is (N,3)
    const int n_slabs = (n_verts + BLK - 1) / BLK;       // 15625 for N=1e6
    int grid = 11 * 256;                                 // 11 blocks/CU persistent
    if (grid > n_slabs) grid = n_slabs;
    lbs_kernel<<<grid, BLK, 0, stream>>>(points, weights, se3, out,
                                         n_verts, n_slabs, grid);
}

// Round 5
// 318.772 us; speedup vs baseline: 1.1281x; 1.1281x over previous
//
#include <hip/hip_runtime.h>

#define NJ    55
#define BLK   64                  // one wave per block: zero barriers
#define SLABF (BLK * NJ)          // 3520 floats = 14080 B per buffer
#define WAIT_VM0 0x0F70           // s_waitcnt vmcnt(0), lgkmcnt=15/expcnt=7 ignored

#define AS_G(p) ((const __attribute__((address_space(1))) void*)(p))
#define AS_L(p) ((__attribute__((address_space(3))) void*)(p))

// Issue the 14 KB slab as 13 full 1-KB LDS-DMA instructions + one 768-B
// masked tail. Lane addressing (base + lane*16B) matches the HW's
// wave-uniform-base + lane*size write pattern exactly. No VGPRs consumed.
__device__ __forceinline__ void dma_slab(const float* __restrict__ src,
                                         float* dst, int lane) {
    #pragma unroll
    for (int i = 0; i < 13; ++i)
        __builtin_amdgcn_global_load_lds(AS_G(src + i * 256 + lane * 4),
                                         AS_L(dst + i * 256 + lane * 4), 16, 0, 0);
    if (lane < 48)
        __builtin_amdgcn_global_load_lds(AS_G(src + 13 * 256 + lane * 4),
                                         AS_L(dst + 13 * 256 + lane * 4), 16, 0, 0);
}

// Double-buffered wave-autonomous LBS:
//   iter i: [prefetch points_{i+1}] [DMA slab_{i+1} -> nxt buffer]
//           [compute slab i from cur buffer: ds_read + FMA, DMA stays in flight]
//           [store out_i] [s_waitcnt vmcnt(0)] [swap buffers]
// Points for iter i+1 are covered by the bottom drain, so the epilogue never
// adds a vmem wait mid-compute. 2 x 14080 B LDS -> 5 blocks/CU, each block
// keeping ~14 KB of DMA outstanding under its compute phase.
__global__ __launch_bounds__(BLK) void lbs_kernel(
    const float* __restrict__ points,
    const float* __restrict__ weights,
    const float* __restrict__ se3,
    float* __restrict__ out,
    int n_verts, int n_slabs, int gstride)
{
    __shared__ __align__(16) float sA[SLABF];
    __shared__ __align__(16) float sB[SLABF];

    const int lane = threadIdx.x;
    int s = blockIdx.x;
    if (s >= n_slabs) return;

    float* cur = sA;
    float* nxt = sB;

    // ---- prologue: points_0 + DMA slab_0 -> cur, full drain
    float px, py, pz;
    {
        const int n = s * BLK + lane;
        const int nc = (n < n_verts) ? n : (n_verts - 1);
        px = points[nc * 3 + 0];
        py = points[nc * 3 + 1];
        pz = points[nc * 3 + 2];
        const int rows = min(BLK, n_verts - s * BLK);
        if (rows == BLK) {
            dma_slab(weights + (size_t)s * SLABF, cur, lane);
        } else {
            const float* src = weights + (size_t)s * SLABF;
            for (int i = lane; i < rows * NJ; i += BLK) cur[i] = src[i];
        }
        __builtin_amdgcn_s_waitcnt(WAIT_VM0);
    }

    for (;;) {
        const int snext = s + gstride;
        const bool have_next = (snext < n_slabs);

        // ---- issue next slab's DMA + next points (no waits here)
        float pxn, pyn, pzn;
        if (have_next) {
            const int n2 = snext * BLK + lane;
            const int nc2 = (n2 < n_verts) ? n2 : (n_verts - 1);
            pxn = points[nc2 * 3 + 0];
            pyn = points[nc2 * 3 + 1];
            pzn = points[nc2 * 3 + 2];
            const int rows = min(BLK, n_verts - snext * BLK);
            if (rows == BLK) {
                dma_slab(weights + (size_t)snext * SLABF, nxt, lane);
            } else {
                const float* src = weights + (size_t)snext * SLABF;
                for (int i = lane; i < rows * NJ; i += BLK) nxt[i] = src[i];
            }
        }

        // ---- compute current slab (lgkm only; DMA rides under this)
        float a[12];
        #pragma unroll
        for (int e = 0; e < 12; ++e) a[e] = 0.f;

        const float* wr = &cur[lane * NJ];      // stride 55: 2-way alias = free
        const float4* M = (const float4*)se3;   // uniform addr -> s_load, K$

        #pragma unroll 5
        for (int j = 0; j < NJ; ++j) {
            const float w = wr[j];
            const float4 r0 = M[j * 4 + 0];
            const float4 r1 = M[j * 4 + 1];
            const float4 r2 = M[j * 4 + 2];     // row 3 of each SE3 unused
            a[0] += w * r0.x; a[1] += w * r0.y; a[2]  += w * r0.z; a[3]  += w * r0.w;
            a[4] += w * r1.x; a[5] += w * r1.y; a[6]  += w * r1.z; a[7]  += w * r1.w;
            a[8] += w * r2.x; a[9] += w * r2.y; a[10] += w * r2.z; a[11] += w * r2.w;
        }

        const int n = s * BLK + lane;
        if (n < n_verts) {
            float* po = out + (size_t)n * 3;
            po[0] = a[0] * px + a[1] * py + a[2]  * pz + a[3];
            po[1] = a[4] * px + a[5] * py + a[6]  * pz + a[7];
            po[2] = a[8] * px + a[9] * py + a[10] * pz + a[11];
        }

        if (!have_next) return;

        // ---- drain DMA (+ next points), swap buffers
        __builtin_amdgcn_s_waitcnt(WAIT_VM0);
        float* t = cur; cur = nxt; nxt = t;
        px = pxn; py = pyn; pz = pzn;
        s = snext;
    }
}

extern "C" void kernel_launch(void* const* d_in, const int* in_sizes, int n_in,
                              void* d_out, int out_size, void* d_ws, size_t ws_size,
                              hipStream_t stream) {
    const float* points  = (const float*)d_in[0];
    const float* weights = (const float*)d_in[1];
    const float* se3     = (const float*)d_in[2];
    float* out = (float*)d_out;

    const int n_verts = in_sizes[0] / 3;              // points is (N,3)
    const int n_slabs = (n_verts + BLK - 1) / BLK;    // 15625 for N=1e6
    int grid = 5 * 256;                               // 5 blocks/CU (LDS-limited), persistent
    if (grid > n_slabs) grid = n_slabs;
    lbs_kernel<<<grid, BLK, 0, stream>>>(points, weights, se3, out,
                                         n_verts, n_slabs, grid);
}